// Round 10
// baseline (185.678 us; speedup 1.0000x reference)
//
#include <hip/hip_runtime.h>

// MCLLoss: masked L1 loss over 5 overlapping value-ranges of real_img.
// Ranges: (-1,1), (-1,-.5), (-.5,0), (0,.5), (.5,1) — inclusive bounds,
// masks overlap; class_mask takes the LAST matching range index.
// Output layout: [loss, losses[5], class_mask_rescaled[N]]; rescale = cls*0.5-1.
//
// R10: wave-granular probe. All prior rounds (63-68us) shared one invariant:
// 256-thread 4-wave blocks + __syncthreads epilogue + <=8 wg/CU (Occ ~62%).
// Now: 128-thread (2-wave) blocks x 16384 -> 16 wg/CU = 32 waves/CU (100%),
// NO __syncthreads / NO LDS in main kernel — each wave reduces and fires its
// own atomics (256 banks, chain depth 128). Waves self-stagger; no convoy.

#define N_BANKS 256
#define BANK_F  16   // floats per bank (64 B line): sums at [0..4], counts at [8..12]
#define TPB 128      // 2 waves per block
#define G_PER_T 2    // float4 groups per thread
#define BLK_F4 (TPB * G_PER_T)   // 256 float4 per block

__device__ __forceinline__ void proc_elem(float pv, float rv,
                                          float s[5], unsigned int c[5],
                                          float& ov) {
    float d = fabsf(pv - rv);
    bool geM1  = rv >= -1.0f;
    bool leM05 = rv <= -0.5f;
    bool geM05 = rv >= -0.5f;
    bool le0   = rv <=  0.0f;
    bool ge0   = rv >=  0.0f;
    bool le05  = rv <=  0.5f;
    bool ge05  = rv >=  0.5f;
    bool le1   = rv <=  1.0f;
    bool in0 = geM1  && le1;
    bool in1 = geM1  && leM05;
    bool in2 = geM05 && le0;
    bool in3 = ge0   && le05;
    bool in4 = ge05  && le1;
    s[0] += in0 ? d : 0.f;  c[0] += in0;
    s[1] += in1 ? d : 0.f;  c[1] += in1;
    s[2] += in2 ? d : 0.f;  c[2] += in2;
    s[3] += in3 ? d : 0.f;  c[3] += in3;
    s[4] += in4 ? d : 0.f;  c[4] += in4;
    int cls = in4 ? 4 : (in3 ? 3 : (in2 ? 2 : (in1 ? 1 : 0)));
    ov = 0.5f * (float)cls - 1.0f;
}

__device__ __forceinline__ void proc_group(int i, const float4& p, const float4& r,
                                           float s[5], unsigned int c[5],
                                           float* __restrict__ mask_out) {
    float ov[4];
    proc_elem(p.x, r.x, s, c, ov[0]);
    proc_elem(p.y, r.y, s, c, ov[1]);
    proc_elem(p.z, r.z, s, c, ov[2]);
    proc_elem(p.w, r.w, s, c, ov[3]);
    // mask_out = d_out+6: 8-byte aligned only -> float2 stores (R7 showed
    // realignment is neutral; L2 merges half-lines into full HBM lines).
    float2* mo = (float2*)(mask_out + 4 * (size_t)i);
    mo[0] = make_float2(ov[0], ov[1]);
    mo[1] = make_float2(ov[2], ov[3]);
}

__global__ __launch_bounds__(TPB, 8) void mcl_main(
    const float* __restrict__ pre, const float* __restrict__ real,
    float* __restrict__ mask_out, float* __restrict__ acc, int n4, int n)
{
    float s[5] = {0.f, 0.f, 0.f, 0.f, 0.f};
    unsigned int c[5] = {0u, 0u, 0u, 0u, 0u};

    const int t = threadIdx.x;
    const int i0 = blockIdx.x * BLK_F4 + t;
    const int i1 = i0 + TPB;
    const bool v0 = i0 < n4;
    const bool v1 = i1 < n4;

    const float4* pre4  = (const float4*)pre;
    const float4* real4 = (const float4*)real;

    // all four 16B loads upfront (64 B in flight per thread)
    float4 p0, r0, p1, r1;
    if (v0) { p0 = pre4[i0]; r0 = real4[i0]; }
    if (v1) { p1 = pre4[i1]; r1 = real4[i1]; }

    if (v0) proc_group(i0, p0, r0, s, c, mask_out);
    if (v1) proc_group(i1, p1, r1, s, c, mask_out);

    // scalar tail (n not divisible by 4)
    {
        int tail_base = n4 * 4;
        int tail = n - tail_base;
        int gtid = blockIdx.x * TPB + t;
        if (gtid < tail) {
            int idx = tail_base + gtid;
            float ov;
            proc_elem(pre[idx], real[idx], s, c, ov);
            mask_out[idx] = ov;
        }
    }

    // wave64 butterfly reduction — per wave, NO cross-wave sync needed
#pragma unroll
    for (int j = 0; j < 5; ++j) {
#pragma unroll
        for (int off = 32; off > 0; off >>= 1) {
            s[j] += __shfl_down(s[j], off, 64);
            c[j] += __shfl_down(c[j], off, 64);
        }
    }

    // lane 0 of each wave fires its own 10 atomics into its bank
    int lane = t & 63;
    int wave = t >> 6;
    if (lane == 0) {
        float* bank = acc + ((blockIdx.x * 2 + wave) & (N_BANKS - 1)) * BANK_F;
#pragma unroll
        for (int j = 0; j < 5; ++j) {
            atomicAdd(&bank[j], s[j]);                        // sums at [0..4]
            atomicAdd((unsigned int*)bank + 8 + j, c[j]);     // counts at [8..12]
        }
    }
}

__global__ void mcl_final(const float* __restrict__ acc, float* __restrict__ out)
{
    // one wave: lane l sums banks l, l+64, l+128, l+192, then butterfly
    int l = threadIdx.x;
    float s[5];
    unsigned int c[5];
#pragma unroll
    for (int j = 0; j < 5; ++j) { s[j] = 0.f; c[j] = 0u; }
#pragma unroll
    for (int b = 0; b < N_BANKS / 64; ++b) {
        const float* bank = acc + (b * 64 + l) * BANK_F;
#pragma unroll
        for (int j = 0; j < 5; ++j) {
            s[j] += bank[j];
            c[j] += ((const unsigned int*)bank)[8 + j];
        }
    }
#pragma unroll
    for (int j = 0; j < 5; ++j) {
#pragma unroll
        for (int off = 32; off > 0; off >>= 1) {
            s[j] += __shfl_down(s[j], off, 64);
            c[j] += __shfl_down(c[j], off, 64);
        }
    }
    if (l == 0) {
        float total = 0.f;
#pragma unroll
        for (int j = 0; j < 5; ++j) {
            unsigned int cnt = c[j];
            unsigned int denom = cnt > 1u ? cnt : 1u;
            float lv = (cnt == 0u) ? 0.f : (s[j] / (float)denom) * 0.2f;
            out[1 + j] = lv;
            total += lv;
        }
        out[0] = total;
    }
}

extern "C" void kernel_launch(void* const* d_in, const int* in_sizes, int n_in,
                              void* d_out, int out_size, void* d_ws, size_t ws_size,
                              hipStream_t stream) {
    const float* pre  = (const float*)d_in[0];
    const float* real = (const float*)d_in[1];
    float* out = (float*)d_out;
    int n = in_sizes[0];
    int n4 = n / 4;

    float* acc = (float*)d_ws;  // 256 banks x 16 floats = 16 KB

    // d_ws re-poisoned to 0xAA before every timed call — zero each launch.
    (void)hipMemsetAsync(d_ws, 0, N_BANKS * BANK_F * sizeof(float), stream);

    int blocks = (n4 + BLK_F4 - 1) / BLK_F4;       // 16384 for N=16M
    if (blocks < 1) blocks = 1;
    mcl_main<<<blocks, TPB, 0, stream>>>(pre, real, out + 6, acc, n4, n);
    mcl_final<<<1, 64, 0, stream>>>(acc, out);
}